// Round 5
// baseline (1103.672 us; speedup 1.0000x reference)
//
#include <hip/hip_runtime.h>
#include <hip/hip_bf16.h>

// SimpleGNN round 5: kill scatter_edges' 17x write amplification (85MB for 4.8MB
// of CSR). Fixed-capacity buckets (32 nodes, CAP=576) take one packed 4B word
// per edge; bucket regions fill densely -> L2 write-combining works. Aggregation
// becomes per-bucket LDS accumulate (ds f32 atomics), no rowptr/scan/csr at all.

#define NFEAT 64
#define BKT_SHIFT 5
#define BKT_NODES 32
#define BKT_CAP 576   // lambda=384, 9.8 sigma; guarded anyway

__global__ __launch_bounds__(256) void zero_i32(int* __restrict__ p, int n) {
    int i = blockIdx.x * blockDim.x + threadIdx.x;
    if (i < n) p[i] = 0;
}

__global__ __launch_bounds__(256) void deg_count(const int* __restrict__ dst,
                                                 int* __restrict__ deg, int nE) {
    int i = blockIdx.x * blockDim.x + threadIdx.x;
    if (i < nE) atomicAdd(&deg[dst[i]], 1);
}

__global__ __launch_bounds__(256) void dinv_kernel(const int* __restrict__ deg,
                                                   float* __restrict__ dinv, int n) {
    int i = blockIdx.x * blockDim.x + threadIdx.x;
    if (i < n) dinv[i] = rsqrtf((float)(deg[i] + 1));  // +1 self-loop
}

// Bucket edges by dst>>5; one packed word per edge: (dst&31)<<17 | src.
__global__ __launch_bounds__(256) void bkt_scatter(const int* __restrict__ src,
                                                   const int* __restrict__ dst,
                                                   int* __restrict__ cursor,
                                                   unsigned* __restrict__ bktbuf, int nE) {
    int e = blockIdx.x * blockDim.x + threadIdx.x;
    if (e < nE) {
        int d = dst[e];
        int s = src[e];
        int b = d >> BKT_SHIFT;
        int idx = atomicAdd(&cursor[b], 1);
        if (idx < BKT_CAP)
            bktbuf[(size_t)b * BKT_CAP + idx] =
                ((unsigned)(d & (BKT_NODES - 1)) << 17) | (unsigned)s;
    }
}

// out[r][j] = dinv[r] * sum_k act(in[r][k]) * W[k][j], act = relu(x + bias[k]) if ACT.
template <bool ACT>
__global__ __launch_bounds__(256) void gemm64(const float* __restrict__ in,
                                              const float* __restrict__ W,
                                              const float* __restrict__ bias,
                                              const float* __restrict__ dinv,
                                              float* __restrict__ out, int nRows) {
    __shared__ float wl[64 * 64];
    __shared__ float xrow[4][64];
    const int tid = threadIdx.x;
    const int lane = tid & 63;
    const int w = tid >> 6;

    #pragma unroll
    for (int i = 0; i < 16; i++) wl[tid + i * 256] = W[tid + i * 256];
    float blane = 0.f;
    if (ACT) blane = bias[lane];
    __syncthreads();

    float wcol[64];
    #pragma unroll
    for (int k = 0; k < 64; k++) wcol[k] = wl[k * 64 + lane];  // conflict-free

    const int base = blockIdx.x * 64 + w * 16;
    for (int i = 0; i < 16; i++) {
        int r = base + i;               // wave-uniform
        if (r >= nRows) break;
        float v = in[(size_t)r * NFEAT + lane];
        if (ACT) v = fmaxf(v + blane, 0.f);
        xrow[w][lane] = v;              // wave-private scratch
        float acc = 0.f;
        const float4* x4 = (const float4*)xrow[w];
        #pragma unroll
        for (int kk = 0; kk < 16; kk++) {
            float4 xv = x4[kk];         // broadcast read
            acc = fmaf(xv.x, wcol[kk * 4 + 0], acc);
            acc = fmaf(xv.y, wcol[kk * 4 + 1], acc);
            acc = fmaf(xv.z, wcol[kk * 4 + 2], acc);
            acc = fmaf(xv.w, wcol[kk * 4 + 3], acc);
        }
        out[(size_t)r * NFEAT + lane] = acc * dinv[r];
    }
}

// One block per bucket: LDS-accumulate the bucket's edges, add self term, scale.
// agg[n] = dinv[n] * (hs[n] + sum_{in-edges} hs[src])
__global__ __launch_bounds__(256) void agg_bucket(const float* __restrict__ hs,
                                                  const float* __restrict__ dinv,
                                                  const int* __restrict__ cursor,
                                                  const unsigned* __restrict__ bktbuf,
                                                  float* __restrict__ agg, int nN) {
    __shared__ float acc[BKT_NODES][NFEAT];   // 8 KB
    const int tid = threadIdx.x;
    const int lane = tid & 63;
    const int w = tid >> 6;
    const int b = blockIdx.x;
    const int nodeBase = b << BKT_SHIFT;

    #pragma unroll
    for (int i = 0; i < 8; i++) ((float*)acc)[tid + i * 256] = 0.f;
    __syncthreads();

    int sz = cursor[b];
    sz = sz < BKT_CAP ? sz : BKT_CAP;
    const unsigned* buf = bktbuf + (size_t)b * BKT_CAP;
    for (int i = w; i < sz; i += 4) {
        unsigned pk = buf[i];                    // same addr across lanes -> broadcast
        int s = (int)(pk & 0x1FFFFu);
        int dl = (int)(pk >> 17);
        float v = hs[(size_t)s * NFEAT + lane];  // coalesced 256B gather
        atomicAdd(&acc[dl][lane], v);            // LDS f32 atomic; banks 2-way (free)
    }
    __syncthreads();

    #pragma unroll
    for (int k = 0; k < 8; ++k) {
        int local = w * 8 + k;
        int n = nodeBase + local;
        if (n < nN) {
            float self = hs[(size_t)n * NFEAT + lane];
            agg[(size_t)n * NFEAT + lane] = (acc[local][lane] + self) * dinv[n];
        }
    }
}

// One wave per 64 contiguous nodes: register-accumulate relu(agg+b2) per graph
// segment (batch sorted), flush at boundaries with HW f32 atomics.
__global__ __launch_bounds__(256) void pool_partial(const float* __restrict__ agg,
                                                    const float* __restrict__ b2,
                                                    const int* __restrict__ batch,
                                                    int nN, float* __restrict__ psum) {
    const int lane = threadIdx.x & 63;
    const int w = threadIdx.x >> 6;
    const int n0 = (blockIdx.x * 4 + w) * 64;
    if (n0 >= nN) return;
    const int nEnd = (n0 + 64 < nN) ? n0 + 64 : nN;
    const float b = b2[lane];
    int gprev = batch[n0];
    float acc = 0.f;
    for (int n = n0; n < nEnd; ++n) {
        int g = batch[n];
        if (g != gprev) {           // value-uniform across the wave
            unsafeAtomicAdd(&psum[(size_t)gprev * NFEAT + lane], acc);
            acc = 0.f;
            gprev = g;
        }
        acc += fmaxf(agg[(size_t)n * NFEAT + lane] + b, 0.f);
    }
    unsafeAtomicAdd(&psum[(size_t)gprev * NFEAT + lane], acc);
}

// One block per graph: node count via binary search on sorted batch, mean, 64x10 head.
__global__ __launch_bounds__(64) void final_kernel(const float* __restrict__ psum,
                                                   const int* __restrict__ batch, int nN,
                                                   const float* __restrict__ Wl,
                                                   const float* __restrict__ bl,
                                                   float* __restrict__ out) {
    const int g = blockIdx.x;
    const int j = threadIdx.x;
    int lo = 0, hi = nN;
    while (lo < hi) { int mid = (lo + hi) >> 1; if (batch[mid] < g) lo = mid + 1; else hi = mid; }
    const int start = lo;
    hi = nN;
    while (lo < hi) { int mid = (lo + hi) >> 1; if (batch[mid] < g + 1) lo = mid + 1; else hi = mid; }
    const int cnt = lo - start;
    __shared__ float p[64];
    p[j] = psum[g * 64 + j] / (float)(cnt > 1 ? cnt : 1);
    __syncthreads();
    if (j < 10) {
        float acc = bl[j];
        #pragma unroll
        for (int f = 0; f < 64; f++) acc = fmaf(p[f], Wl[f * 10 + j], acc);
        out[g * 10 + j] = acc;
    }
}

static inline size_t align256(size_t s) { return (s + 255) & ~(size_t)255; }

extern "C" void kernel_launch(void* const* d_in, const int* in_sizes, int n_in,
                              void* d_out, int out_size, void* d_ws, size_t ws_size,
                              hipStream_t stream) {
    const float* x     = (const float*)d_in[0];
    const int*   ei    = (const int*)d_in[1];   // [2][E] flat
    const int*   batch = (const int*)d_in[2];
    const float* W1    = (const float*)d_in[3];
    const float* b1    = (const float*)d_in[4];
    const float* W2    = (const float*)d_in[5];
    const float* b2    = (const float*)d_in[6];
    const float* Wl    = (const float*)d_in[7];
    const float* bl    = (const float*)d_in[8];
    float* out = (float*)d_out;

    const int nN = in_sizes[0] / NFEAT;   // 100000
    const int nE = in_sizes[1] / 2;       // 1200000
    const int nG = 256;
    const int* src = ei;
    const int* dst = ei + nE;
    const int nBkt = (nN + BKT_NODES - 1) >> BKT_SHIFT;   // 3125

    // workspace carve (~59 MB)
    char* w = (char*)d_ws;
    float*    dinv   = (float*)w;    w += align256((size_t)nN * 4);
    int*      deg    = (int*)w;      w += align256((size_t)nN * 4);
    int*      cursor = (int*)w;      w += align256((size_t)nBkt * 4);
    unsigned* bktbuf = (unsigned*)w; w += align256((size_t)nBkt * BKT_CAP * 4);
    float*    hbuf   = (float*)w;    w += align256((size_t)nN * NFEAT * 4);
    float*    agg    = (float*)w;    w += align256((size_t)nN * NFEAT * 4);
    float*    psum   = (float*)w;    w += align256((size_t)nG * NFEAT * 4);

    const int nBlkN   = (nN + 255) / 256;   // 391
    const int nBlkE   = (nE + 255) / 256;   // 4688
    const int nBlkRow = (nN + 63) / 64;     // 1563

    // init + degree + bucketing
    zero_i32<<<nBlkN, 256, 0, stream>>>(deg, nN);
    zero_i32<<<(nBkt + 255) / 256, 256, 0, stream>>>(cursor, nBkt);
    zero_i32<<<(nG * NFEAT + 255) / 256, 256, 0, stream>>>((int*)psum, nG * NFEAT);
    deg_count<<<nBlkE, 256, 0, stream>>>(dst, deg, nE);
    dinv_kernel<<<nBlkN, 256, 0, stream>>>(deg, dinv, nN);
    bkt_scatter<<<nBlkE, 256, 0, stream>>>(src, dst, cursor, bktbuf, nE);

    // layer 1: hs = (x@W1)*dinv ; agg1 = dinv*(hs[n] + sum hs[src])
    gemm64<false><<<nBlkRow, 256, 0, stream>>>(x, W1, nullptr, dinv, hbuf, nN);
    agg_bucket<<<nBkt, 256, 0, stream>>>(hbuf, dinv, cursor, bktbuf, agg, nN);

    // layer 2: input act = relu(agg1 + b1) fused into GEMM
    gemm64<true><<<nBlkRow, 256, 0, stream>>>(agg, W2, b1, dinv, hbuf, nN);
    agg_bucket<<<nBkt, 256, 0, stream>>>(hbuf, dinv, cursor, bktbuf, agg, nN);

    // pool (applies relu(agg+b2)) + head
    pool_partial<<<nBlkN, 256, 0, stream>>>(agg, b2, batch, nN, psum);
    final_kernel<<<nG, 64, 0, stream>>>(psum, batch, nN, Wl, bl, out);
}

// Round 6
// 347.419 us; speedup vs baseline: 3.1768x; 3.1768x over previous
//
#include <hip/hip_runtime.h>
#include <hip/hip_bf16.h>

// SimpleGNN round 6: revert to round-4 structure (CSR + agg_csr, 319us known-good).
// Single change: scatter_edges' csr[] stores are NON-TEMPORAL. Theory: the 85MB
// WRITE_SIZE (17x amplification) came from 4B stores to lines shared-written by
// blocks on all 8 XCDs; incoherent per-XCD L2s emit a 64B partial writeback per
// store. NT stores bypass L2 and merge at the LLC coherence point.

#define NFEAT 64

__global__ __launch_bounds__(256) void zero_i32(int* __restrict__ p, int n) {
    int i = blockIdx.x * blockDim.x + threadIdx.x;
    if (i < n) p[i] = 0;
}

__global__ __launch_bounds__(256) void deg_count(const int* __restrict__ dst,
                                                 int* __restrict__ deg, int nE) {
    int i = blockIdx.x * blockDim.x + threadIdx.x;
    if (i < nE) atomicAdd(&deg[dst[i]], 1);
}

__global__ __launch_bounds__(256) void dinv_kernel(const int* __restrict__ deg,
                                                   float* __restrict__ dinv, int n) {
    int i = blockIdx.x * blockDim.x + threadIdx.x;
    if (i < n) dinv[i] = rsqrtf((float)(deg[i] + 1));  // +1 self-loop
}

// --- exclusive prefix scan of deg -> rowptr (3 kernels) ---
__global__ __launch_bounds__(256) void scan_blocks(const int* __restrict__ deg,
                                                   int* __restrict__ rowptr,
                                                   int* __restrict__ bsums, int n) {
    __shared__ int s[256];
    const int tid = threadIdx.x;
    const int i = blockIdx.x * 256 + tid;
    int v = (i < n) ? deg[i] : 0;
    s[tid] = v;
    __syncthreads();
    #pragma unroll
    for (int off = 1; off < 256; off <<= 1) {
        int t = (tid >= off) ? s[tid - off] : 0;
        __syncthreads();
        s[tid] += t;
        __syncthreads();
    }
    if (i < n) rowptr[i] = s[tid] - v;        // block-local exclusive
    if (tid == 255) bsums[blockIdx.x] = s[255];
}

__global__ __launch_bounds__(512) void scan_bsums(int* __restrict__ bsums, int nb,
                                                  int* __restrict__ rowptr, int nN, int nE) {
    __shared__ int s[512];
    const int tid = threadIdx.x;
    int v = (tid < nb) ? bsums[tid] : 0;
    s[tid] = v;
    __syncthreads();
    #pragma unroll
    for (int off = 1; off < 512; off <<= 1) {
        int t = (tid >= off) ? s[tid - off] : 0;
        __syncthreads();
        s[tid] += t;
        __syncthreads();
    }
    if (tid < nb) bsums[tid] = s[tid] - v;    // exclusive
    if (tid == 0) rowptr[nN] = nE;
}

__global__ __launch_bounds__(256) void scan_add(int* __restrict__ rowptr,
                                                const int* __restrict__ bsums, int n) {
    const int i = blockIdx.x * 256 + threadIdx.x;
    if (i < n) rowptr[i] += bsums[blockIdx.x];
}

__global__ __launch_bounds__(256) void scatter_edges(const int* __restrict__ src,
                                                     const int* __restrict__ dst,
                                                     const int* __restrict__ rowptr,
                                                     int* __restrict__ cnt,
                                                     int* __restrict__ csr, int nE) {
    int e = blockIdx.x * blockDim.x + threadIdx.x;
    if (e < nE) {
        int d = dst[e];
        int s = src[e];
        int pos = rowptr[d] + atomicAdd(&cnt[d], 1);
        __builtin_nontemporal_store(s, &csr[pos]);   // nt: bypass L2, merge at LLC
    }
}

// out[r][j] = dinv[r] * sum_k act(in[r][k]) * W[k][j], act = relu(x + bias[k]) if ACT.
template <bool ACT>
__global__ __launch_bounds__(256) void gemm64(const float* __restrict__ in,
                                              const float* __restrict__ W,
                                              const float* __restrict__ bias,
                                              const float* __restrict__ dinv,
                                              float* __restrict__ out, int nRows) {
    __shared__ float wl[64 * 64];
    __shared__ float xrow[4][64];
    const int tid = threadIdx.x;
    const int lane = tid & 63;
    const int w = tid >> 6;

    #pragma unroll
    for (int i = 0; i < 16; i++) wl[tid + i * 256] = W[tid + i * 256];
    float blane = 0.f;
    if (ACT) blane = bias[lane];
    __syncthreads();

    float wcol[64];
    #pragma unroll
    for (int k = 0; k < 64; k++) wcol[k] = wl[k * 64 + lane];  // conflict-free

    const int base = blockIdx.x * 64 + w * 16;
    for (int i = 0; i < 16; i++) {
        int r = base + i;               // wave-uniform
        if (r >= nRows) break;
        float v = in[(size_t)r * NFEAT + lane];
        if (ACT) v = fmaxf(v + blane, 0.f);
        xrow[w][lane] = v;              // wave-private scratch
        float acc = 0.f;
        const float4* x4 = (const float4*)xrow[w];
        #pragma unroll
        for (int kk = 0; kk < 16; kk++) {
            float4 xv = x4[kk];         // broadcast read
            acc = fmaf(xv.x, wcol[kk * 4 + 0], acc);
            acc = fmaf(xv.y, wcol[kk * 4 + 1], acc);
            acc = fmaf(xv.z, wcol[kk * 4 + 2], acc);
            acc = fmaf(xv.w, wcol[kk * 4 + 3], acc);
        }
        out[(size_t)r * NFEAT + lane] = acc * dinv[r];
    }
}

// One wave per node: acc = hs[n] + sum over in-edges of hs[csr[e]]; agg = acc*dinv[n].
__global__ __launch_bounds__(256) void agg_csr(const float* __restrict__ hs,
                                               const float* __restrict__ dinv,
                                               const int* __restrict__ rowptr,
                                               const int* __restrict__ csr,
                                               float* __restrict__ agg, int nN) {
    const int lane = threadIdx.x & 63;
    int n0 = blockIdx.x * (blockDim.x >> 6) + (threadIdx.x >> 6);
    if (n0 >= nN) return;
    const int n = __builtin_amdgcn_readfirstlane(n0);  // wave-uniform -> s_loads
    const int b = rowptr[n];
    const int e = rowptr[n + 1];
    float acc = hs[(size_t)n * NFEAT + lane];
    int i = b;
    for (; i + 3 < e; i += 4) {
        int s0 = csr[i], s1 = csr[i + 1], s2 = csr[i + 2], s3 = csr[i + 3];
        float v0 = hs[(size_t)s0 * NFEAT + lane];
        float v1 = hs[(size_t)s1 * NFEAT + lane];
        float v2 = hs[(size_t)s2 * NFEAT + lane];
        float v3 = hs[(size_t)s3 * NFEAT + lane];
        acc += v0; acc += v1; acc += v2; acc += v3;
    }
    for (; i < e; ++i) acc += hs[(size_t)csr[i] * NFEAT + lane];
    agg[(size_t)n * NFEAT + lane] = acc * dinv[n];
}

// One wave per 64 contiguous nodes: register-accumulate relu(agg+b2) per graph
// segment (batch sorted), flush at boundaries with HW f32 atomics.
__global__ __launch_bounds__(256) void pool_partial(const float* __restrict__ agg,
                                                    const float* __restrict__ b2,
                                                    const int* __restrict__ batch,
                                                    int nN, float* __restrict__ psum) {
    const int lane = threadIdx.x & 63;
    const int w = threadIdx.x >> 6;
    const int n0 = (blockIdx.x * 4 + w) * 64;
    if (n0 >= nN) return;
    const int nEnd = (n0 + 64 < nN) ? n0 + 64 : nN;
    const float b = b2[lane];
    int gprev = batch[n0];
    float acc = 0.f;
    for (int n = n0; n < nEnd; ++n) {
        int g = batch[n];
        if (g != gprev) {           // value-uniform across the wave
            unsafeAtomicAdd(&psum[(size_t)gprev * NFEAT + lane], acc);
            acc = 0.f;
            gprev = g;
        }
        acc += fmaxf(agg[(size_t)n * NFEAT + lane] + b, 0.f);
    }
    unsafeAtomicAdd(&psum[(size_t)gprev * NFEAT + lane], acc);
}

// One block per graph: node count via binary search on sorted batch, mean, 64x10 head.
__global__ __launch_bounds__(64) void final_kernel(const float* __restrict__ psum,
                                                   const int* __restrict__ batch, int nN,
                                                   const float* __restrict__ Wl,
                                                   const float* __restrict__ bl,
                                                   float* __restrict__ out) {
    const int g = blockIdx.x;
    const int j = threadIdx.x;
    int lo = 0, hi = nN;
    while (lo < hi) { int mid = (lo + hi) >> 1; if (batch[mid] < g) lo = mid + 1; else hi = mid; }
    const int start = lo;
    hi = nN;
    while (lo < hi) { int mid = (lo + hi) >> 1; if (batch[mid] < g + 1) lo = mid + 1; else hi = mid; }
    const int cnt = lo - start;
    __shared__ float p[64];
    p[j] = psum[g * 64 + j] / (float)(cnt > 1 ? cnt : 1);
    __syncthreads();
    if (j < 10) {
        float acc = bl[j];
        #pragma unroll
        for (int f = 0; f < 64; f++) acc = fmaf(p[f], Wl[f * 10 + j], acc);
        out[g * 10 + j] = acc;
    }
}

static inline size_t align256(size_t s) { return (s + 255) & ~(size_t)255; }

extern "C" void kernel_launch(void* const* d_in, const int* in_sizes, int n_in,
                              void* d_out, int out_size, void* d_ws, size_t ws_size,
                              hipStream_t stream) {
    const float* x     = (const float*)d_in[0];
    const int*   ei    = (const int*)d_in[1];   // [2][E] flat
    const int*   batch = (const int*)d_in[2];
    const float* W1    = (const float*)d_in[3];
    const float* b1    = (const float*)d_in[4];
    const float* W2    = (const float*)d_in[5];
    const float* b2    = (const float*)d_in[6];
    const float* Wl    = (const float*)d_in[7];
    const float* bl    = (const float*)d_in[8];
    float* out = (float*)d_out;

    const int nN = in_sizes[0] / NFEAT;   // 100000
    const int nE = in_sizes[1] / 2;       // 1200000
    const int nG = 256;
    const int* src = ei;
    const int* dst = ei + nE;

    // workspace carve (~57 MB)
    char* w = (char*)d_ws;
    float* dinv   = (float*)w; w += align256((size_t)nN * 4);
    int*   deg    = (int*)w;   w += align256((size_t)nN * 4);        // reused as scatter cursor
    int*   rowptr = (int*)w;   w += align256((size_t)(nN + 1) * 4);
    int*   bsums  = (int*)w;   w += align256((size_t)512 * 4);
    int*   csr    = (int*)w;   w += align256((size_t)nE * 4);
    float* hbuf   = (float*)w; w += align256((size_t)nN * NFEAT * 4);
    float* agg    = (float*)w; w += align256((size_t)nN * NFEAT * 4);
    float* psum   = (float*)w; w += align256((size_t)nG * NFEAT * 4);

    const int nBlkN   = (nN + 255) / 256;   // 391
    const int nBlkE   = (nE + 255) / 256;   // 4688
    const int nBlkRow = (nN + 63) / 64;     // 1563
    const int nBlkAgg = (nN + 3) / 4;       // 25000

    // degree + pool-buffer init
    zero_i32<<<nBlkN, 256, 0, stream>>>(deg, nN);
    zero_i32<<<(nG * NFEAT + 255) / 256, 256, 0, stream>>>((int*)psum, nG * NFEAT);
    deg_count<<<nBlkE, 256, 0, stream>>>(dst, deg, nE);
    dinv_kernel<<<nBlkN, 256, 0, stream>>>(deg, dinv, nN);

    // CSR build (rebuilt every call; deterministic workload)
    scan_blocks<<<nBlkN, 256, 0, stream>>>(deg, rowptr, bsums, nN);
    scan_bsums<<<1, 512, 0, stream>>>(bsums, nBlkN, rowptr, nN, nE);
    scan_add<<<nBlkN, 256, 0, stream>>>(rowptr, bsums, nN);
    zero_i32<<<nBlkN, 256, 0, stream>>>(deg, nN);   // deg -> cursor
    scatter_edges<<<nBlkE, 256, 0, stream>>>(src, dst, rowptr, deg, csr, nE);

    // layer 1: hs = (x@W1)*dinv ; agg1 = dinv*(hs[n] + sum hs[src])
    gemm64<false><<<nBlkRow, 256, 0, stream>>>(x, W1, nullptr, dinv, hbuf, nN);
    agg_csr<<<nBlkAgg, 256, 0, stream>>>(hbuf, dinv, rowptr, csr, agg, nN);

    // layer 2: input act = relu(agg1 + b1) fused into GEMM
    gemm64<true><<<nBlkRow, 256, 0, stream>>>(agg, W2, b1, dinv, hbuf, nN);
    agg_csr<<<nBlkAgg, 256, 0, stream>>>(hbuf, dinv, rowptr, csr, agg, nN);

    // pool (applies relu(agg+b2)) + head (binary-search counts, fused mean)
    pool_partial<<<nBlkN, 256, 0, stream>>>(agg, b2, batch, nN, psum);
    final_kernel<<<nG, 64, 0, stream>>>(psum, batch, nN, Wl, bl, out);
}

// Round 7
// 323.602 us; speedup vs baseline: 3.4106x; 1.0736x over previous
//
#include <hip/hip_runtime.h>
#include <hip/hip_bf16.h>

// SimpleGNN round 7: round-4 structure (NT store reverted — falsified, cost +35us).
// Experiment: hs (GEMM output / gather source) stored as bf16. Halves agg_csr
// gather bytes (256B->128B per edge) and makes the hs working set 12.8MB (better
// L2 residency). agg/psum/out remain f32; one bf16 rounding per layer.

#define NFEAT 64

__global__ __launch_bounds__(256) void zero_i32(int* __restrict__ p, int n) {
    int i = blockIdx.x * blockDim.x + threadIdx.x;
    if (i < n) p[i] = 0;
}

__global__ __launch_bounds__(256) void deg_count(const int* __restrict__ dst,
                                                 int* __restrict__ deg, int nE) {
    int i = blockIdx.x * blockDim.x + threadIdx.x;
    if (i < nE) atomicAdd(&deg[dst[i]], 1);
}

__global__ __launch_bounds__(256) void dinv_kernel(const int* __restrict__ deg,
                                                   float* __restrict__ dinv, int n) {
    int i = blockIdx.x * blockDim.x + threadIdx.x;
    if (i < n) dinv[i] = rsqrtf((float)(deg[i] + 1));  // +1 self-loop
}

// --- exclusive prefix scan of deg -> rowptr (3 kernels) ---
__global__ __launch_bounds__(256) void scan_blocks(const int* __restrict__ deg,
                                                   int* __restrict__ rowptr,
                                                   int* __restrict__ bsums, int n) {
    __shared__ int s[256];
    const int tid = threadIdx.x;
    const int i = blockIdx.x * 256 + tid;
    int v = (i < n) ? deg[i] : 0;
    s[tid] = v;
    __syncthreads();
    #pragma unroll
    for (int off = 1; off < 256; off <<= 1) {
        int t = (tid >= off) ? s[tid - off] : 0;
        __syncthreads();
        s[tid] += t;
        __syncthreads();
    }
    if (i < n) rowptr[i] = s[tid] - v;        // block-local exclusive
    if (tid == 255) bsums[blockIdx.x] = s[255];
}

__global__ __launch_bounds__(512) void scan_bsums(int* __restrict__ bsums, int nb,
                                                  int* __restrict__ rowptr, int nN, int nE) {
    __shared__ int s[512];
    const int tid = threadIdx.x;
    int v = (tid < nb) ? bsums[tid] : 0;
    s[tid] = v;
    __syncthreads();
    #pragma unroll
    for (int off = 1; off < 512; off <<= 1) {
        int t = (tid >= off) ? s[tid - off] : 0;
        __syncthreads();
        s[tid] += t;
        __syncthreads();
    }
    if (tid < nb) bsums[tid] = s[tid] - v;    // exclusive
    if (tid == 0) rowptr[nN] = nE;
}

__global__ __launch_bounds__(256) void scan_add(int* __restrict__ rowptr,
                                                const int* __restrict__ bsums, int n) {
    const int i = blockIdx.x * 256 + threadIdx.x;
    if (i < n) rowptr[i] += bsums[blockIdx.x];
}

__global__ __launch_bounds__(256) void scatter_edges(const int* __restrict__ src,
                                                     const int* __restrict__ dst,
                                                     const int* __restrict__ rowptr,
                                                     int* __restrict__ cnt,
                                                     int* __restrict__ csr, int nE) {
    int e = blockIdx.x * blockDim.x + threadIdx.x;
    if (e < nE) {
        int d = dst[e];
        int pos = rowptr[d] + atomicAdd(&cnt[d], 1);
        csr[pos] = src[e];
    }
}

// out[r][j] = bf16( dinv[r] * sum_k act(in[r][k]) * W[k][j] ), act = relu(x+bias) if ACT.
template <bool ACT>
__global__ __launch_bounds__(256) void gemm64(const float* __restrict__ in,
                                              const float* __restrict__ W,
                                              const float* __restrict__ bias,
                                              const float* __restrict__ dinv,
                                              __hip_bfloat16* __restrict__ out, int nRows) {
    __shared__ float wl[64 * 64];
    __shared__ float xrow[4][64];
    const int tid = threadIdx.x;
    const int lane = tid & 63;
    const int w = tid >> 6;

    #pragma unroll
    for (int i = 0; i < 16; i++) wl[tid + i * 256] = W[tid + i * 256];
    float blane = 0.f;
    if (ACT) blane = bias[lane];
    __syncthreads();

    float wcol[64];
    #pragma unroll
    for (int k = 0; k < 64; k++) wcol[k] = wl[k * 64 + lane];  // conflict-free

    const int base = blockIdx.x * 64 + w * 16;
    for (int i = 0; i < 16; i++) {
        int r = base + i;               // wave-uniform
        if (r >= nRows) break;
        float v = in[(size_t)r * NFEAT + lane];
        if (ACT) v = fmaxf(v + blane, 0.f);
        xrow[w][lane] = v;              // wave-private scratch
        float acc = 0.f;
        const float4* x4 = (const float4*)xrow[w];
        #pragma unroll
        for (int kk = 0; kk < 16; kk++) {
            float4 xv = x4[kk];         // broadcast read
            acc = fmaf(xv.x, wcol[kk * 4 + 0], acc);
            acc = fmaf(xv.y, wcol[kk * 4 + 1], acc);
            acc = fmaf(xv.z, wcol[kk * 4 + 2], acc);
            acc = fmaf(xv.w, wcol[kk * 4 + 3], acc);
        }
        out[(size_t)r * NFEAT + lane] = __float2bfloat16(acc * dinv[r]);
    }
}

// One wave per node: acc = hs[n] + sum over in-edges of hs[csr[e]]; agg = acc*dinv[n].
// hs is bf16 (128B per gathered row); accumulation in f32.
__global__ __launch_bounds__(256) void agg_csr(const __hip_bfloat16* __restrict__ hs,
                                               const float* __restrict__ dinv,
                                               const int* __restrict__ rowptr,
                                               const int* __restrict__ csr,
                                               float* __restrict__ agg, int nN) {
    const int lane = threadIdx.x & 63;
    int n0 = blockIdx.x * (blockDim.x >> 6) + (threadIdx.x >> 6);
    if (n0 >= nN) return;
    const int n = __builtin_amdgcn_readfirstlane(n0);  // wave-uniform -> s_loads
    const int b = rowptr[n];
    const int e = rowptr[n + 1];
    float acc = __bfloat162float(hs[(size_t)n * NFEAT + lane]);
    int i = b;
    for (; i + 3 < e; i += 4) {
        int s0 = csr[i], s1 = csr[i + 1], s2 = csr[i + 2], s3 = csr[i + 3];
        float v0 = __bfloat162float(hs[(size_t)s0 * NFEAT + lane]);
        float v1 = __bfloat162float(hs[(size_t)s1 * NFEAT + lane]);
        float v2 = __bfloat162float(hs[(size_t)s2 * NFEAT + lane]);
        float v3 = __bfloat162float(hs[(size_t)s3 * NFEAT + lane]);
        acc += v0; acc += v1; acc += v2; acc += v3;
    }
    for (; i < e; ++i) acc += __bfloat162float(hs[(size_t)csr[i] * NFEAT + lane]);
    agg[(size_t)n * NFEAT + lane] = acc * dinv[n];
}

// One wave per 64 contiguous nodes: register-accumulate relu(agg+b2) per graph
// segment (batch sorted), flush at boundaries with HW f32 atomics.
__global__ __launch_bounds__(256) void pool_partial(const float* __restrict__ agg,
                                                    const float* __restrict__ b2,
                                                    const int* __restrict__ batch,
                                                    int nN, float* __restrict__ psum) {
    const int lane = threadIdx.x & 63;
    const int w = threadIdx.x >> 6;
    const int n0 = (blockIdx.x * 4 + w) * 64;
    if (n0 >= nN) return;
    const int nEnd = (n0 + 64 < nN) ? n0 + 64 : nN;
    const float b = b2[lane];
    int gprev = batch[n0];
    float acc = 0.f;
    for (int n = n0; n < nEnd; ++n) {
        int g = batch[n];
        if (g != gprev) {           // value-uniform across the wave
            unsafeAtomicAdd(&psum[(size_t)gprev * NFEAT + lane], acc);
            acc = 0.f;
            gprev = g;
        }
        acc += fmaxf(agg[(size_t)n * NFEAT + lane] + b, 0.f);
    }
    unsafeAtomicAdd(&psum[(size_t)gprev * NFEAT + lane], acc);
}

// One block per graph: node count via binary search on sorted batch, mean, 64x10 head.
__global__ __launch_bounds__(64) void final_kernel(const float* __restrict__ psum,
                                                   const int* __restrict__ batch, int nN,
                                                   const float* __restrict__ Wl,
                                                   const float* __restrict__ bl,
                                                   float* __restrict__ out) {
    const int g = blockIdx.x;
    const int j = threadIdx.x;
    int lo = 0, hi = nN;
    while (lo < hi) { int mid = (lo + hi) >> 1; if (batch[mid] < g) lo = mid + 1; else hi = mid; }
    const int start = lo;
    hi = nN;
    while (lo < hi) { int mid = (lo + hi) >> 1; if (batch[mid] < g + 1) lo = mid + 1; else hi = mid; }
    const int cnt = lo - start;
    __shared__ float p[64];
    p[j] = psum[g * 64 + j] / (float)(cnt > 1 ? cnt : 1);
    __syncthreads();
    if (j < 10) {
        float acc = bl[j];
        #pragma unroll
        for (int f = 0; f < 64; f++) acc = fmaf(p[f], Wl[f * 10 + j], acc);
        out[g * 10 + j] = acc;
    }
}

static inline size_t align256(size_t s) { return (s + 255) & ~(size_t)255; }

extern "C" void kernel_launch(void* const* d_in, const int* in_sizes, int n_in,
                              void* d_out, int out_size, void* d_ws, size_t ws_size,
                              hipStream_t stream) {
    const float* x     = (const float*)d_in[0];
    const int*   ei    = (const int*)d_in[1];   // [2][E] flat
    const int*   batch = (const int*)d_in[2];
    const float* W1    = (const float*)d_in[3];
    const float* b1    = (const float*)d_in[4];
    const float* W2    = (const float*)d_in[5];
    const float* b2    = (const float*)d_in[6];
    const float* Wl    = (const float*)d_in[7];
    const float* bl    = (const float*)d_in[8];
    float* out = (float*)d_out;

    const int nN = in_sizes[0] / NFEAT;   // 100000
    const int nE = in_sizes[1] / 2;       // 1200000
    const int nG = 256;
    const int* src = ei;
    const int* dst = ei + nE;

    // workspace carve (~44 MB)
    char* w = (char*)d_ws;
    float* dinv   = (float*)w; w += align256((size_t)nN * 4);
    int*   deg    = (int*)w;   w += align256((size_t)nN * 4);        // reused as scatter cursor
    int*   rowptr = (int*)w;   w += align256((size_t)(nN + 1) * 4);
    int*   bsums  = (int*)w;   w += align256((size_t)512 * 4);
    int*   csr    = (int*)w;   w += align256((size_t)nE * 4);
    __hip_bfloat16* hbuf = (__hip_bfloat16*)w; w += align256((size_t)nN * NFEAT * 2);
    float* agg    = (float*)w; w += align256((size_t)nN * NFEAT * 4);
    float* psum   = (float*)w; w += align256((size_t)nG * NFEAT * 4);

    const int nBlkN   = (nN + 255) / 256;   // 391
    const int nBlkE   = (nE + 255) / 256;   // 4688
    const int nBlkRow = (nN + 63) / 64;     // 1563
    const int nBlkAgg = (nN + 3) / 4;       // 25000

    // degree + pool-buffer init
    zero_i32<<<nBlkN, 256, 0, stream>>>(deg, nN);
    zero_i32<<<(nG * NFEAT + 255) / 256, 256, 0, stream>>>((int*)psum, nG * NFEAT);
    deg_count<<<nBlkE, 256, 0, stream>>>(dst, deg, nE);
    dinv_kernel<<<nBlkN, 256, 0, stream>>>(deg, dinv, nN);

    // CSR build (rebuilt every call; deterministic workload)
    scan_blocks<<<nBlkN, 256, 0, stream>>>(deg, rowptr, bsums, nN);
    scan_bsums<<<1, 512, 0, stream>>>(bsums, nBlkN, rowptr, nN, nE);
    scan_add<<<nBlkN, 256, 0, stream>>>(rowptr, bsums, nN);
    zero_i32<<<nBlkN, 256, 0, stream>>>(deg, nN);   // deg -> cursor
    scatter_edges<<<nBlkE, 256, 0, stream>>>(src, dst, rowptr, deg, csr, nE);

    // layer 1: hs = bf16((x@W1)*dinv) ; agg1 = dinv*(hs[n] + sum hs[src])
    gemm64<false><<<nBlkRow, 256, 0, stream>>>(x, W1, nullptr, dinv, hbuf, nN);
    agg_csr<<<nBlkAgg, 256, 0, stream>>>(hbuf, dinv, rowptr, csr, agg, nN);

    // layer 2: input act = relu(agg1 + b1) fused into GEMM (agg stays f32)
    gemm64<true><<<nBlkRow, 256, 0, stream>>>(agg, W2, b1, dinv, hbuf, nN);
    agg_csr<<<nBlkAgg, 256, 0, stream>>>(hbuf, dinv, rowptr, csr, agg, nN);

    // pool (applies relu(agg+b2)) + head (binary-search counts, fused mean)
    pool_partial<<<nBlkN, 256, 0, stream>>>(agg, b2, batch, nN, psum);
    final_kernel<<<nG, 64, 0, stream>>>(psum, batch, nN, Wl, bl, out);
}

// Round 8
// 289.583 us; speedup vs baseline: 3.8113x; 1.1175x over previous
//
#include <hip/hip_runtime.h>
#include <hip/hip_bf16.h>

// SimpleGNN round 8: consolidation + overlap. bf16 hs kept (neutral perf, halves
// gemm writes). Changes vs round 7:
//  - gemm1 fused into scatter kernel (disjoint block ranges; VALU-bound gemm
//    overlaps write-bound scatter)
//  - dinv folded into scan_blocks; cursor-zero folded into scan_add
//  - zero_i32 kernels replaced by hipMemsetAsync
// 14 dispatches -> 10 kernels + 2 memsets.

#define NFEAT 64

__global__ __launch_bounds__(256) void deg_count(const int* __restrict__ dst,
                                                 int* __restrict__ deg, int nE) {
    int i = blockIdx.x * blockDim.x + threadIdx.x;
    if (i < nE) atomicAdd(&deg[dst[i]], 1);
}

// --- exclusive prefix scan of deg -> rowptr; also emits dinv = rsqrt(deg+1) ---
__global__ __launch_bounds__(256) void scan_blocks(const int* __restrict__ deg,
                                                   int* __restrict__ rowptr,
                                                   int* __restrict__ bsums,
                                                   float* __restrict__ dinv, int n) {
    __shared__ int s[256];
    const int tid = threadIdx.x;
    const int i = blockIdx.x * 256 + tid;
    int v = (i < n) ? deg[i] : 0;
    if (i < n) dinv[i] = rsqrtf((float)(v + 1));   // +1 self-loop
    s[tid] = v;
    __syncthreads();
    #pragma unroll
    for (int off = 1; off < 256; off <<= 1) {
        int t = (tid >= off) ? s[tid - off] : 0;
        __syncthreads();
        s[tid] += t;
        __syncthreads();
    }
    if (i < n) rowptr[i] = s[tid] - v;        // block-local exclusive
    if (tid == 255) bsums[blockIdx.x] = s[255];
}

__global__ __launch_bounds__(512) void scan_bsums(int* __restrict__ bsums, int nb,
                                                  int* __restrict__ rowptr, int nN, int nE) {
    __shared__ int s[512];
    const int tid = threadIdx.x;
    int v = (tid < nb) ? bsums[tid] : 0;
    s[tid] = v;
    __syncthreads();
    #pragma unroll
    for (int off = 1; off < 512; off <<= 1) {
        int t = (tid >= off) ? s[tid - off] : 0;
        __syncthreads();
        s[tid] += t;
        __syncthreads();
    }
    if (tid < nb) bsums[tid] = s[tid] - v;    // exclusive
    if (tid == 0) rowptr[nN] = nE;
}

// rowptr finalize + zero the scatter cursor (same index space)
__global__ __launch_bounds__(256) void scan_add(int* __restrict__ rowptr,
                                                const int* __restrict__ bsums,
                                                int* __restrict__ cursor, int n) {
    const int i = blockIdx.x * 256 + threadIdx.x;
    if (i < n) {
        rowptr[i] += bsums[blockIdx.x];
        cursor[i] = 0;
    }
}

// GEMM body: out[r][j] = bf16( dinv[r] * sum_k act(in[r][k]) * W[k][j] )
template <bool ACT>
__device__ __forceinline__ void gemm_rows(const float* __restrict__ in,
                                          const float* __restrict__ W,
                                          const float* __restrict__ bias,
                                          const float* __restrict__ dinv,
                                          __hip_bfloat16* __restrict__ out,
                                          int nRows, int rowBlock,
                                          float* wl, float* xrow) {
    const int tid = threadIdx.x;
    const int lane = tid & 63;
    const int w = tid >> 6;

    #pragma unroll
    for (int i = 0; i < 16; i++) wl[tid + i * 256] = W[tid + i * 256];
    float blane = 0.f;
    if (ACT) blane = bias[lane];
    __syncthreads();

    float wcol[64];
    #pragma unroll
    for (int k = 0; k < 64; k++) wcol[k] = wl[k * 64 + lane];  // conflict-free

    const int base = rowBlock * 64 + w * 16;
    for (int i = 0; i < 16; i++) {
        int r = base + i;               // wave-uniform
        if (r >= nRows) break;
        float v = in[(size_t)r * NFEAT + lane];
        if (ACT) v = fmaxf(v + blane, 0.f);
        xrow[w * 64 + lane] = v;        // wave-private scratch
        float acc = 0.f;
        const float4* x4 = (const float4*)(xrow + w * 64);
        #pragma unroll
        for (int kk = 0; kk < 16; kk++) {
            float4 xv = x4[kk];         // broadcast read
            acc = fmaf(xv.x, wcol[kk * 4 + 0], acc);
            acc = fmaf(xv.y, wcol[kk * 4 + 1], acc);
            acc = fmaf(xv.z, wcol[kk * 4 + 2], acc);
            acc = fmaf(xv.w, wcol[kk * 4 + 3], acc);
        }
        out[(size_t)r * NFEAT + lane] = __float2bfloat16(acc * dinv[r]);
    }
}

// Fused: blocks [0,nGemmBlk) run layer-1 GEMM (VALU-bound); the rest scatter
// edges into CSR (write-bound). Independent work, complementary pipes.
__global__ __launch_bounds__(256) void gemm1_scatter(
        const float* __restrict__ x, const float* __restrict__ W1,
        const float* __restrict__ dinv, __hip_bfloat16* __restrict__ hbuf, int nN,
        const int* __restrict__ src, const int* __restrict__ dst,
        const int* __restrict__ rowptr, int* __restrict__ cursor,
        int* __restrict__ csr, int nE, int nGemmBlk) {
    __shared__ float wl[64 * 64];
    __shared__ float xrow[4 * 64];
    const int b = blockIdx.x;
    if (b < nGemmBlk) {
        gemm_rows<false>(x, W1, nullptr, dinv, hbuf, nN, b, wl, xrow);
    } else {
        int e = (b - nGemmBlk) * 256 + threadIdx.x;
        if (e < nE) {
            int d = dst[e];
            int pos = rowptr[d] + atomicAdd(&cursor[d], 1);
            csr[pos] = src[e];
        }
    }
}

// Standalone layer-2 GEMM (input act = relu(agg + b1))
__global__ __launch_bounds__(256) void gemm64_l2(const float* __restrict__ in,
                                                 const float* __restrict__ W,
                                                 const float* __restrict__ bias,
                                                 const float* __restrict__ dinv,
                                                 __hip_bfloat16* __restrict__ out, int nRows) {
    __shared__ float wl[64 * 64];
    __shared__ float xrow[4 * 64];
    gemm_rows<true>(in, W, bias, dinv, out, nRows, blockIdx.x, wl, xrow);
}

// One wave per node: acc = hs[n] + sum over in-edges of hs[csr[e]]; agg = acc*dinv[n].
__global__ __launch_bounds__(256) void agg_csr(const __hip_bfloat16* __restrict__ hs,
                                               const float* __restrict__ dinv,
                                               const int* __restrict__ rowptr,
                                               const int* __restrict__ csr,
                                               float* __restrict__ agg, int nN) {
    const int lane = threadIdx.x & 63;
    int n0 = blockIdx.x * (blockDim.x >> 6) + (threadIdx.x >> 6);
    if (n0 >= nN) return;
    const int n = __builtin_amdgcn_readfirstlane(n0);  // wave-uniform -> s_loads
    const int b = rowptr[n];
    const int e = rowptr[n + 1];
    float acc = __bfloat162float(hs[(size_t)n * NFEAT + lane]);
    int i = b;
    for (; i + 3 < e; i += 4) {
        int s0 = csr[i], s1 = csr[i + 1], s2 = csr[i + 2], s3 = csr[i + 3];
        float v0 = __bfloat162float(hs[(size_t)s0 * NFEAT + lane]);
        float v1 = __bfloat162float(hs[(size_t)s1 * NFEAT + lane]);
        float v2 = __bfloat162float(hs[(size_t)s2 * NFEAT + lane]);
        float v3 = __bfloat162float(hs[(size_t)s3 * NFEAT + lane]);
        acc += v0; acc += v1; acc += v2; acc += v3;
    }
    for (; i < e; ++i) acc += __bfloat162float(hs[(size_t)csr[i] * NFEAT + lane]);
    agg[(size_t)n * NFEAT + lane] = acc * dinv[n];
}

// One wave per 64 contiguous nodes: register-accumulate relu(agg+b2) per graph
// segment (batch sorted), flush at boundaries with HW f32 atomics.
__global__ __launch_bounds__(256) void pool_partial(const float* __restrict__ agg,
                                                    const float* __restrict__ b2,
                                                    const int* __restrict__ batch,
                                                    int nN, float* __restrict__ psum) {
    const int lane = threadIdx.x & 63;
    const int w = threadIdx.x >> 6;
    const int n0 = (blockIdx.x * 4 + w) * 64;
    if (n0 >= nN) return;
    const int nEnd = (n0 + 64 < nN) ? n0 + 64 : nN;
    const float b = b2[lane];
    int gprev = batch[n0];
    float acc = 0.f;
    for (int n = n0; n < nEnd; ++n) {
        int g = batch[n];
        if (g != gprev) {           // value-uniform across the wave
            unsafeAtomicAdd(&psum[(size_t)gprev * NFEAT + lane], acc);
            acc = 0.f;
            gprev = g;
        }
        acc += fmaxf(agg[(size_t)n * NFEAT + lane] + b, 0.f);
    }
    unsafeAtomicAdd(&psum[(size_t)gprev * NFEAT + lane], acc);
}

// One block per graph: node count via binary search on sorted batch, mean, 64x10 head.
__global__ __launch_bounds__(64) void final_kernel(const float* __restrict__ psum,
                                                   const int* __restrict__ batch, int nN,
                                                   const float* __restrict__ Wl,
                                                   const float* __restrict__ bl,
                                                   float* __restrict__ out) {
    const int g = blockIdx.x;
    const int j = threadIdx.x;
    int lo = 0, hi = nN;
    while (lo < hi) { int mid = (lo + hi) >> 1; if (batch[mid] < g) lo = mid + 1; else hi = mid; }
    const int start = lo;
    hi = nN;
    while (lo < hi) { int mid = (lo + hi) >> 1; if (batch[mid] < g + 1) lo = mid + 1; else hi = mid; }
    const int cnt = lo - start;
    __shared__ float p[64];
    p[j] = psum[g * 64 + j] / (float)(cnt > 1 ? cnt : 1);
    __syncthreads();
    if (j < 10) {
        float acc = bl[j];
        #pragma unroll
        for (int f = 0; f < 64; f++) acc = fmaf(p[f], Wl[f * 10 + j], acc);
        out[g * 10 + j] = acc;
    }
}

static inline size_t align256(size_t s) { return (s + 255) & ~(size_t)255; }

extern "C" void kernel_launch(void* const* d_in, const int* in_sizes, int n_in,
                              void* d_out, int out_size, void* d_ws, size_t ws_size,
                              hipStream_t stream) {
    const float* x     = (const float*)d_in[0];
    const int*   ei    = (const int*)d_in[1];   // [2][E] flat
    const int*   batch = (const int*)d_in[2];
    const float* W1    = (const float*)d_in[3];
    const float* b1    = (const float*)d_in[4];
    const float* W2    = (const float*)d_in[5];
    const float* b2    = (const float*)d_in[6];
    const float* Wl    = (const float*)d_in[7];
    const float* bl    = (const float*)d_in[8];
    float* out = (float*)d_out;

    const int nN = in_sizes[0] / NFEAT;   // 100000
    const int nE = in_sizes[1] / 2;       // 1200000
    const int nG = 256;
    const int* src = ei;
    const int* dst = ei + nE;

    // workspace carve (~44 MB)
    char* w = (char*)d_ws;
    float* dinv   = (float*)w; w += align256((size_t)nN * 4);
    int*   deg    = (int*)w;   w += align256((size_t)nN * 4);        // reused as scatter cursor
    int*   rowptr = (int*)w;   w += align256((size_t)(nN + 1) * 4);
    int*   bsums  = (int*)w;   w += align256((size_t)512 * 4);
    int*   csr    = (int*)w;   w += align256((size_t)nE * 4);
    __hip_bfloat16* hbuf = (__hip_bfloat16*)w; w += align256((size_t)nN * NFEAT * 2);
    float* agg    = (float*)w; w += align256((size_t)nN * NFEAT * 4);
    float* psum   = (float*)w; w += align256((size_t)nG * NFEAT * 4);

    const int nBlkN   = (nN + 255) / 256;   // 391
    const int nBlkE   = (nE + 255) / 256;   // 4688
    const int nBlkRow = (nN + 63) / 64;     // 1563
    const int nBlkAgg = (nN + 3) / 4;       // 25000

    // init (graph-capturable async memsets)
    hipMemsetAsync(deg, 0, (size_t)nN * 4, stream);
    hipMemsetAsync(psum, 0, (size_t)nG * NFEAT * 4, stream);

    // degree histogram -> {rowptr scan, dinv}
    deg_count<<<nBlkE, 256, 0, stream>>>(dst, deg, nE);
    scan_blocks<<<nBlkN, 256, 0, stream>>>(deg, rowptr, bsums, dinv, nN);
    scan_bsums<<<1, 512, 0, stream>>>(bsums, nBlkN, rowptr, nN, nE);
    scan_add<<<nBlkN, 256, 0, stream>>>(rowptr, bsums, deg /*cursor*/, nN);

    // layer-1 GEMM overlapped with CSR scatter (independent, complementary-bound)
    gemm1_scatter<<<nBlkRow + nBlkE, 256, 0, stream>>>(
        x, W1, dinv, hbuf, nN, src, dst, rowptr, deg /*cursor*/, csr, nE, nBlkRow);
    agg_csr<<<nBlkAgg, 256, 0, stream>>>(hbuf, dinv, rowptr, csr, agg, nN);

    // layer 2
    gemm64_l2<<<nBlkRow, 256, 0, stream>>>(agg, W2, b1, dinv, hbuf, nN);
    agg_csr<<<nBlkAgg, 256, 0, stream>>>(hbuf, dinv, rowptr, csr, agg, nN);

    // pool (applies relu(agg+b2)) + head (binary-search counts, fused mean)
    pool_partial<<<nBlkN, 256, 0, stream>>>(agg, b2, batch, nN, psum);
    final_kernel<<<nG, 64, 0, stream>>>(psum, batch, nN, Wl, bl, out);
}